// Round 18
// baseline (835.567 us; speedup 1.0000x reference)
//
#include <hip/hip_runtime.h>
#include <hip/hip_bf16.h>
#include <stdint.h>

#define N_ROWS 8192
#define DIM 768
#define NF 32768
#define TOPK 32
#define CANDCAP 72
#define RTHRESH 44

typedef __attribute__((ext_vector_type(8))) short bf16x8;
typedef __attribute__((ext_vector_type(8))) short short8;
typedef __attribute__((ext_vector_type(4))) float f32x4;

__device__ inline void async_ld16(const void* g, void* l) {
  __builtin_amdgcn_global_load_lds(
      (const __attribute__((address_space(1))) unsigned int*)g,
      (__attribute__((address_space(3))) unsigned int*)l, 16, 0, 0);
}

__device__ inline unsigned short f2bf(float f) {
  union { float f; unsigned u; } c; c.f = f;
  unsigned r = c.u + 0x7FFFu + ((c.u >> 16) & 1u);  // RNE
  return (unsigned short)(r >> 16);
}

__device__ inline float bf2f(unsigned short u) {
  union { unsigned u; float f; } c; c.u = ((unsigned)u) << 16;
  return c.f;
}

// barrier that is ALSO a compiler-level memory fence
__device__ inline void block_barrier_fenced() {
  __builtin_amdgcn_s_barrier();
  asm volatile("" ::: "memory");
  __builtin_amdgcn_sched_barrier(0);
}

// ---- fused preprocessing: one launch, disjoint block ranges ---------------
#define PREP_LN_BLOCKS 8192
#define PREP_CV_BLOCKS 24576
#define PREP_TR_BLOCKS 24576
__global__ __launch_bounds__(256) void k_prep(const float* __restrict__ x,
                                              const float* __restrict__ pre_bias,
                                              const float* __restrict__ enc,
                                              const float* __restrict__ dec,
                                              unsigned short* __restrict__ xh,
                                              float* __restrict__ meanA,
                                              float* __restrict__ stdA,
                                              unsigned short* __restrict__ ench,
                                              unsigned short* __restrict__ dect) {
  int bid = blockIdx.x;
  int tid = threadIdx.x;

  if (bid < PREP_LN_BLOCKS) {
    int row = bid;
    int lane = tid & 63, wv = tid >> 6;
    const float* xr = x + (size_t)row * DIM;
    float a0 = xr[tid], a1 = xr[tid + 256], a2 = xr[tid + 512];
    __shared__ float red[8];
    float s = a0 + a1 + a2;
    for (int off = 32; off > 0; off >>= 1) s += __shfl_down(s, off);
    if (lane == 0) red[wv] = s;
    __syncthreads();
    float mean;
    if (tid == 0) { mean = (red[0] + red[1] + red[2] + red[3]) / (float)DIM; red[4] = mean; }
    __syncthreads();
    mean = red[4];
    float d0 = a0 - mean, d1 = a1 - mean, d2 = a2 - mean;
    float ss = d0 * d0 + d1 * d1 + d2 * d2;
    for (int off = 32; off > 0; off >>= 1) ss += __shfl_down(ss, off);
    if (lane == 0) red[wv] = ss;
    __syncthreads();
    float stdv;
    if (tid == 0) {
      float var = (red[0] + red[1] + red[2] + red[3]) / (float)DIM;
      stdv = sqrtf(var + 1e-5f);
      red[5] = stdv;
      meanA[row] = mean;
      stdA[row] = stdv;
    }
    __syncthreads();
    stdv = red[5];
    float inv = 1.0f / stdv;
    unsigned short* xo = xh + (size_t)row * DIM;
    xo[tid]       = f2bf(d0 * inv - pre_bias[tid]);
    xo[tid + 256] = f2bf(d1 * inv - pre_bias[tid + 256]);
    xo[tid + 512] = f2bf(d2 * inv - pre_bias[tid + 512]);
  } else if (bid < PREP_LN_BLOCKS + PREP_CV_BLOCKS) {
    int i = (bid - PREP_LN_BLOCKS) * 256 + tid;
    const int n4 = NF * DIM / 4;
    if (i < n4) {
      float4 v = ((const float4*)enc)[i];
      ushort4 r;
      r.x = f2bf(v.x); r.y = f2bf(v.y); r.z = f2bf(v.z); r.w = f2bf(v.w);
      ((ushort4*)ench)[i] = r;
    }
  } else {
    int local = bid - PREP_LN_BLOCKS - PREP_CV_BLOCKS;
    __shared__ float t[32][33];
    int tx = tid & 31, ty = tid >> 5;  // 32 x 8
    int fb = (local & 1023) * 32, cb = (local >> 10) * 32;
    for (int i = 0; i < 4; i++) {
      int r = ty + i * 8;
      t[r][tx] = dec[(size_t)(cb + r) * NF + fb + tx];
    }
    __syncthreads();
    for (int i = 0; i < 4; i++) {
      int r = ty + i * 8;
      dect[(size_t)(fb + r) * DIM + cb + tx] = f2bf(t[tx][r]);
    }
  }
}

// ---- 256x128 bf16 MFMA GEMM, BK=32, 3-buffer ring, 2-deep prefetch, -------
// ---- ONE barrier per K-step, counted vmcnt(3), 8 waves of 64x64, ----------
// ---- K-loop FULLY UNROLLED (addresses fold to immediates; kills VALU) -----
// cand6[row][slice(256)][0..5] = (orderable_fp32_key & 0xFFFFFF00) | col7
// LDS: ring sA[3]x16K @0 + sB[3]x8K @49152 (72 KB); epilogue reuse:
//   sC[128][129] f32 @0 (66048 B) + m6[512][6] int @66048 (12288 B) = 78336
__global__ __launch_bounds__(512, 4) void k_gemm(const unsigned short* __restrict__ xh,
                                                 const unsigned short* __restrict__ ench,
                                                 const float* __restrict__ latent_bias,
                                                 unsigned* __restrict__ cand6) {
  __shared__ __align__(16) char smem[78336];
  int tid = threadIdx.x;
  int lane = tid & 63;
  int w = tid >> 6;
  int wr = w >> 1, wc = w & 1;      // 4 M-waves x 2 N-waves; wave out = 64x64
  int lid = blockIdx.x + blockIdx.y * gridDim.x;   // [0, 8192)
  int xcd = lid & 7;
  int u = (lid >> 3) & 31;          // position within 4(by) x 8(bx) super-tile
  int s = lid >> 8;                 // [0,32) super-tile sweep
  int bx = s * 8 + (u & 7);         // N tile (feature / 128) = slice index
  int by = xcd * 4 + (u >> 3);      // M tile (row / 256)
  const int fr = lane & 15, hi = lane >> 4;

  const char* Ab = (const char*)(xh + (size_t)by * 256 * DIM);
  const char* Bb = (const char*)(ench + (size_t)bx * 128 * DIM);

  int rA[2], cA[2], rB, cB;
#pragma unroll
  for (int i = 0; i < 2; i++) {
    int L = i * 8192 + tid * 16;
    int R = L >> 7;
    int ss = ((L >> 4) & 7) ^ (R & 7);
    rA[i] = (R << 1) + (ss >> 2);
    cA[i] = (ss & 3) << 4;
  }
  {
    int L = tid * 16;
    int R = L >> 7;
    int ss = ((L >> 4) & 7) ^ (R & 7);
    rB = (R << 1) + (ss >> 2);
    cB = (ss & 3) << 4;
  }

  int offA[4], offB[4];
#pragma unroll
  for (int m = 0; m < 4; m++) {
    int r = wr * 64 + m * 16 + fr;
    int R = r >> 1;
    int slot = ((r & 1) << 2) + hi;
    offA[m] = R * 128 + ((slot ^ (R & 7)) << 4);
  }
#pragma unroll
  for (int n = 0; n < 4; n++) {
    int r = wc * 64 + n * 16 + fr;
    int R = r >> 1;
    int slot = ((r & 1) << 2) + hi;
    offB[n] = R * 128 + ((slot ^ (R & 7)) << 4);
  }

  f32x4 acc[4][4];
#pragma unroll
  for (int m = 0; m < 4; m++)
#pragma unroll
    for (int n = 0; n < 4; n++) {
      f32x4 z = {0.f, 0.f, 0.f, 0.f};
      acc[m][n] = z;
    }

#define STAGE(kt, b)                                                          \
  do {                                                                        \
    char* dA = smem + (b) * 16384;                                            \
    char* dB = smem + 49152 + (b) * 8192;                                     \
    _Pragma("unroll") for (int i = 0; i < 2; i++)                             \
        async_ld16(Ab + (size_t)rA[i] * (DIM * 2) + (kt) * 64 + cA[i],        \
                   dA + i * 8192 + tid * 16);                                 \
    async_ld16(Bb + (size_t)rB * (DIM * 2) + (kt) * 64 + cB,                  \
               dB + tid * 16);                                                \
  } while (0)

  // prologue: 2 tiles in flight (2-deep prefetch)
  STAGE(0, 0);
  STAGE(1, 1);

#pragma unroll
  for (int kt = 0; kt < 24; kt++) {
    int b = kt % 3;
    if (kt + 1 < 24) asm volatile("s_waitcnt vmcnt(3)" ::: "memory");
    else             asm volatile("s_waitcnt vmcnt(0)" ::: "memory");
    block_barrier_fenced();
    if (kt + 2 < 24) STAGE(kt + 2, (kt + 2) % 3);

    const char* pA = smem + b * 16384;
    const char* pB = smem + 49152 + b * 8192;
    bf16x8 af[4], bv[4];
#pragma unroll
    for (int m = 0; m < 4; m++) af[m] = *(const bf16x8*)(pA + offA[m]);
#pragma unroll
    for (int n = 0; n < 4; n++) bv[n] = *(const bf16x8*)(pB + offB[n]);
    __builtin_amdgcn_s_setprio(1);
#pragma unroll
    for (int m = 0; m < 4; m++)
#pragma unroll
      for (int n = 0; n < 4; n++)
        acc[m][n] = __builtin_amdgcn_mfma_f32_16x16x32_bf16(af[m], bv[n], acc[m][n], 0, 0, 0);
    __builtin_amdgcn_s_setprio(0);
  }
#undef STAGE
  __syncthreads();  // all compute(23) reads done before ring is reused as sC

  // ---- fused epilogue: two 128-row half-passes over the 256x128 output ----
  float* sC = (float*)smem;                 // [128][129]
  int* m6 = (int*)(smem + 66048);           // [512][6], slot = q*128 + r
#pragma unroll
  for (int p = 0; p < 2; p++) {
    if ((wr >> 1) == p) {
#pragma unroll
      for (int n = 0; n < 4; n++) {
        int lcol = wc * 64 + n * 16 + fr;
        float lbv = latent_bias[bx * 128 + lcol];
#pragma unroll
        for (int m = 0; m < 4; m++) {
          int lr = (wr & 1) * 64 + m * 16 + hi * 4;
#pragma unroll
          for (int j = 0; j < 4; j++)
            sC[(lr + j) * 129 + lcol] = acc[m][n][j] + lbv;
        }
      }
    }
    __syncthreads();
    {
      int r = tid & 127, q = tid >> 7;
      const float* cr = sC + r * 129 + q * 32;
      unsigned c0 = 0, c1 = 0, c2 = 0, c3 = 0, c4 = 0, c5 = 0;
      for (int c = 0; c < 32; c++) {
        union { float f; unsigned u; } cv; cv.f = cr[c];
        unsigned key = ((int)cv.u < 0) ? ~cv.u : (cv.u | 0x80000000u);
        unsigned pk = (key & 0xFFFFFF00u) | (unsigned)(q * 32 + c);
        if (pk > c0) {
          bool b1 = pk > c1, b2 = pk > c2, b3 = pk > c3, b4 = pk > c4, b5 = pk > c5;
          c0 = b1 ? c1 : pk;
          c1 = b1 ? (b2 ? c2 : pk) : c1;
          c2 = b2 ? (b3 ? c3 : pk) : c2;
          c3 = b3 ? (b4 ? c4 : pk) : c3;
          c4 = b4 ? (b5 ? c5 : pk) : c4;
          c5 = b5 ? pk : c5;
        }
      }
      int* mp = m6 + (q * 128 + r) * 6;
      mp[0] = (int)c0; mp[1] = (int)c1; mp[2] = (int)c2;
      mp[3] = (int)c3; mp[4] = (int)c4; mp[5] = (int)c5;
    }
    __syncthreads();
    if (tid < 128) {
      const int* L0 = m6 + (0 * 128 + tid) * 6;
      const int* L1 = m6 + (1 * 128 + tid) * 6;
      const int* L2 = m6 + (2 * 128 + tid) * 6;
      const int* L3 = m6 + (3 * 128 + tid) * 6;
      int i0 = 5, i1 = 5, i2 = 5, i3 = 5;
      unsigned* dst = cand6 + ((size_t)(by * 256 + p * 128 + tid) * 256 + bx) * 6;
#pragma unroll
      for (int k = 0; k < 6; k++) {
        unsigned v0 = (i0 >= 0) ? (unsigned)L0[i0] : 0u;
        unsigned v1 = (i1 >= 0) ? (unsigned)L1[i1] : 0u;
        unsigned v2 = (i2 >= 0) ? (unsigned)L2[i2] : 0u;
        unsigned v3 = (i3 >= 0) ? (unsigned)L3[i3] : 0u;
        unsigned best = v0; int bq = 0;
        if (v1 > best) { best = v1; bq = 1; }
        if (v2 > best) { best = v2; bq = 2; }
        if (v3 > best) { best = v3; bq = 3; }
        dst[k] = best;
        if (bq == 0) i0--; else if (bq == 1) i1--; else if (bq == 2) i2--; else i3--;
      }
    }
    __syncthreads();
  }
}

// --- pass A: screen + refine + exact top-32 -> hv/hf (working set L3-fits) -
__global__ __launch_bounds__(256) void k_selA(const float* __restrict__ x,
                                              const float* __restrict__ pre_bias,
                                              const float* __restrict__ latent_bias,
                                              const float* __restrict__ enc,
                                              const unsigned* __restrict__ cand6,
                                              const float* __restrict__ meanA,
                                              const float* __restrict__ stdA,
                                              float* __restrict__ hvg,
                                              int* __restrict__ hfg) {
  __shared__ __align__(16) float xn[DIM];
  __shared__ int hist[512];
  __shared__ int hist2[128];
  __shared__ int sb_bstar, sb_chi, sb_cnt;
  __shared__ unsigned sb_tau;
  __shared__ int cand[CANDCAP];
  __shared__ float exactv[128];
  __shared__ int self_[128];
  __shared__ float hv[TOPK];
  __shared__ int hf[TOPK];

  int row = blockIdx.x, tid = threadIdx.x, lane = tid & 63;
  float m = meanA[row], s = stdA[row], inv = 1.0f / s;
  const float* xr = x + (size_t)row * DIM;
  for (int i = tid; i < DIM; i += 256)
    xn[i] = (xr[i] - m) * inv - pre_bias[i];

  // ---------------- screen phase (LDS-resident, verbatim) -----------------
  const unsigned* src = cand6 + (size_t)row * 1536 + tid * 6;
  unsigned pc0 = src[0], pc1 = src[1], pc2 = src[2],
           pc3 = src[3], pc4 = src[4], pc5 = src[5];

  hist[tid] = 0; hist[tid + 256] = 0;
  if (tid < 128) hist2[tid] = 0;
  if (tid == 0) sb_cnt = 0;
  __syncthreads();

  atomicAdd(&hist[pc0 >> 23], 1);
  atomicAdd(&hist[pc1 >> 23], 1);
  atomicAdd(&hist[pc2 >> 23], 1);
  atomicAdd(&hist[pc3 >> 23], 1);
  atomicAdd(&hist[pc4 >> 23], 1);
  atomicAdd(&hist[pc5 >> 23], 1);
  __syncthreads();

  if (tid < 64) {
    int b = lane * 8;
    int h0 = hist[b], h1 = hist[b+1], h2 = hist[b+2], h3 = hist[b+3];
    int h4 = hist[b+4], h5 = hist[b+5], h6 = hist[b+6], h7 = hist[b+7];
    int s7 = h7, s6 = h6 + s7, s5 = h5 + s6, s4 = h4 + s5;
    int s3 = h3 + s4, s2 = h2 + s3, s1 = h1 + s2, s0 = h0 + s1;
    int tot = s0, acc = tot;
#pragma unroll
    for (int off = 1; off <= 32; off <<= 1) {
      int t = __shfl_down(acc, off);
      if (lane + off < 64) acc += t;
    }
    int excl = acc - tot;
    int best = -1, bs = 0, hb = 0;
    if (excl + s0 >= RTHRESH) { best = b + 0; bs = excl + s0; hb = h0; }
    if (excl + s1 >= RTHRESH) { best = b + 1; bs = excl + s1; hb = h1; }
    if (excl + s2 >= RTHRESH) { best = b + 2; bs = excl + s2; hb = h2; }
    if (excl + s3 >= RTHRESH) { best = b + 3; bs = excl + s3; hb = h3; }
    if (excl + s4 >= RTHRESH) { best = b + 4; bs = excl + s4; hb = h4; }
    if (excl + s5 >= RTHRESH) { best = b + 5; bs = excl + s5; hb = h5; }
    if (excl + s6 >= RTHRESH) { best = b + 6; bs = excl + s6; hb = h6; }
    if (excl + s7 >= RTHRESH) { best = b + 7; bs = excl + s7; hb = h7; }
#pragma unroll
    for (int off = 32; off > 0; off >>= 1) {
      int ob = __shfl_down(best, off), obs = __shfl_down(bs, off), ohb = __shfl_down(hb, off);
      if (lane + off < 64 && ob > best) { best = ob; bs = obs; hb = ohb; }
    }
    if (lane == 0) { sb_bstar = best; sb_chi = bs - hb; }
  }
  __syncthreads();
  int bstar = sb_bstar, chi = sb_chi;

  if ((int)(pc0 >> 23) == bstar) atomicAdd(&hist2[(pc0 >> 16) & 127], 1);
  if ((int)(pc1 >> 23) == bstar) atomicAdd(&hist2[(pc1 >> 16) & 127], 1);
  if ((int)(pc2 >> 23) == bstar) atomicAdd(&hist2[(pc2 >> 16) & 127], 1);
  if ((int)(pc3 >> 23) == bstar) atomicAdd(&hist2[(pc3 >> 16) & 127], 1);
  if ((int)(pc4 >> 23) == bstar) atomicAdd(&hist2[(pc4 >> 16) & 127], 1);
  if ((int)(pc5 >> 23) == bstar) atomicAdd(&hist2[(pc5 >> 16) & 127], 1);
  __syncthreads();

  if (tid < 64) {
    int g0 = hist2[lane * 2], g1 = hist2[lane * 2 + 1];
    int s1 = g1, s0 = g0 + g1;
    int tot = s0, acc = tot;
#pragma unroll
    for (int off = 1; off <= 32; off <<= 1) {
      int t = __shfl_down(acc, off);
      if (lane + off < 64) acc += t;
    }
    int excl = acc - tot;
    int best = -1;
    if (chi + excl + s0 >= RTHRESH) best = lane * 2;
    if (chi + excl + s1 >= RTHRESH) best = lane * 2 + 1;
#pragma unroll
    for (int off = 32; off > 0; off >>= 1) {
      int ob = __shfl_down(best, off);
      if (lane + off < 64 && ob > best) best = ob;
    }
    if (lane == 0) sb_tau = ((unsigned)((bstar << 7) | best)) << 16;
  }
  __syncthreads();

  unsigned tau = sb_tau;
#define EMIT(PC)                                                   \
  if ((PC) >= tau) {                                               \
    int pos = atomicAdd(&sb_cnt, 1);                               \
    if (pos < CANDCAP) cand[pos] = tid * 128 + (int)((PC) & 127u); \
  }
  EMIT(pc0) EMIT(pc1) EMIT(pc2) EMIT(pc3) EMIT(pc4) EMIT(pc5)
#undef EMIT
  __syncthreads();

  int cnt = sb_cnt < CANDCAP ? sb_cnt : CANDCAP;  // in [RTHRESH, CANDCAP]
  if (tid < 128) {
    self_[tid] = (tid < cnt) ? cand[tid] : 0x7FFFFFF;
    exactv[tid] = -3.0e38f;
  }
  __syncthreads();

  // ---------------- refine phase (FROZEN order; unroll 8 = bit-exact) -----
#pragma unroll
  for (int pass = 0; pass < 2; pass++) {
    int g = pass * 64 + (tid >> 2), t4 = tid & 3;
    if (g < cnt) {
      int f = self_[g];
      const float4* xp = (const float4*)xn;
      const float4* wp = (const float4*)(enc + (size_t)f * DIM);
      float acc = 0.f;
#pragma unroll 8
      for (int i = t4; i < DIM / 4; i += 4) {
        float4 a = xp[i], b = wp[i];
        acc = fmaf(a.x, b.x, acc);
        acc = fmaf(a.y, b.y, acc);
        acc = fmaf(a.z, b.z, acc);
        acc = fmaf(a.w, b.w, acc);
      }
      acc += __shfl_xor(acc, 1);
      acc += __shfl_xor(acc, 2);
      if (t4 == 0) exactv[g] = acc + latent_bias[f];
    }
  }
  __syncthreads();

  // ---------------- exact top-32 (FROZEN) ---------------------------------
  if (tid < 64) {
    float v0 = exactv[lane];      int f0 = self_[lane];
    float v1 = exactv[lane + 64]; int f1 = self_[lane + 64];
    for (int r = 0; r < TOPK; r++) {
      float bv = v0; int bf = f0;
      if (v1 > bv || (v1 == bv && f1 < bf)) { bv = v1; bf = f1; }
#pragma unroll
      for (int off = 32; off > 0; off >>= 1) {
        float ov = __shfl_down(bv, off);
        int of = __shfl_down(bf, off);
        if (lane + off < 64 && (ov > bv || (ov == bv && of < bf))) { bv = ov; bf = of; }
      }
      bv = __shfl(bv, 0);
      bf = __shfl(bf, 0);
      if (lane == 0) { hv[r] = bv > 0.f ? bv : 0.f; hf[r] = bf; }
      if (f0 == bf) v0 = -3.0e38f;
      if (f1 == bf) v1 = -3.0e38f;
    }
  }
  __syncthreads();

  if (tid < TOPK) {
    hvg[(size_t)row * TOPK + tid] = hv[tid];
    hfg[(size_t)row * TOPK + tid] = hf[tid];
  }
}

// --- pass B: decode + de-normalize (dect fully L3-resident) ----------------
__global__ __launch_bounds__(256) void k_selB(const float* __restrict__ pre_bias,
                                              const unsigned short* __restrict__ dect,
                                              const float* __restrict__ hvg,
                                              const int* __restrict__ hfg,
                                              const float* __restrict__ meanA,
                                              const float* __restrict__ stdA,
                                              float* __restrict__ out) {
  __shared__ float hv[TOPK];
  __shared__ int hf[TOPK];
  int row = blockIdx.x, tid = threadIdx.x;
  float m = meanA[row], s = stdA[row];
  if (tid < TOPK) {
    hv[tid] = hvg[(size_t)row * TOPK + tid];
    hf[tid] = hfg[(size_t)row * TOPK + tid];
  }
  __syncthreads();

  float* orow = out + (size_t)row * DIM;
#pragma unroll
  for (int t = 0; t < 3; t++) {
    int c = tid + t * 256;
    float acc = pre_bias[c];
    for (int j = 0; j < TOPK; j++)
      acc = fmaf(hv[j], bf2f(dect[(size_t)hf[j] * DIM + c]), acc);
    orow[c] = acc * s + m;
  }
}

extern "C" void kernel_launch(void* const* d_in, const int* in_sizes, int n_in,
                              void* d_out, int out_size, void* d_ws, size_t ws_size,
                              hipStream_t stream) {
  const float* x   = (const float*)d_in[0];
  const float* pb  = (const float*)d_in[1];
  const float* lb  = (const float*)d_in[2];
  const float* enc = (const float*)d_in[3];
  const float* dec = (const float*)d_in[4];
  float* out = (float*)d_out;

  // fixed workspace layout (bytes)
  const size_t off_xh   = 0;            // 12,582,912
  const size_t off_ench = 12582912;     // 50,331,648
  const size_t off_dect = 62914560;     // 50,331,648 (bf16)
  const size_t off_mean = 113246208;    // 32,768
  const size_t off_std  = 113278976;    // 32,768
  const size_t off_c6   = 113311744;    // 8192*256*6*4 = 50,331,648
  const size_t off_hv   = 163643392;    // 8192*32*4 = 1,048,576
  const size_t off_hf   = 164691968;    // 1,048,576
  if (ws_size < 165740544) return;      // cannot run

  char* ws = (char*)d_ws;
  unsigned short* xh   = (unsigned short*)(ws + off_xh);
  unsigned short* ench = (unsigned short*)(ws + off_ench);
  unsigned short* dect = (unsigned short*)(ws + off_dect);
  float* meanA = (float*)(ws + off_mean);
  float* stdA  = (float*)(ws + off_std);
  unsigned* cand6 = (unsigned*)(ws + off_c6);
  float* hvg = (float*)(ws + off_hv);
  int*   hfg = (int*)(ws + off_hf);

  hipLaunchKernelGGL(k_prep,
                     dim3(PREP_LN_BLOCKS + PREP_CV_BLOCKS + PREP_TR_BLOCKS),
                     dim3(256), 0, stream,
                     x, pb, enc, dec, xh, meanA, stdA, ench, dect);

  hipLaunchKernelGGL(k_gemm, dim3(NF / 128, N_ROWS / 256), dim3(512), 0, stream,
                     xh, ench, lb, cand6);

  hipLaunchKernelGGL(k_selA, dim3(N_ROWS), dim3(256), 0, stream,
                     x, pb, lb, enc, cand6, meanA, stdA, hvg, hfg);

  hipLaunchKernelGGL(k_selB, dim3(N_ROWS), dim3(256), 0, stream,
                     pb, dect, hvg, hfg, meanA, stdA, out);
}

// Round 19
// 807.532 us; speedup vs baseline: 1.0347x; 1.0347x over previous
//
#include <hip/hip_runtime.h>
#include <hip/hip_bf16.h>
#include <stdint.h>

#define N_ROWS 8192
#define DIM 768
#define NF 32768
#define TOPK 32
#define CANDCAP 72
#define RTHRESH 44

typedef __attribute__((ext_vector_type(8))) short bf16x8;
typedef __attribute__((ext_vector_type(8))) short short8;
typedef __attribute__((ext_vector_type(4))) float f32x4;

__device__ inline void async_ld16(const void* g, void* l) {
  __builtin_amdgcn_global_load_lds(
      (const __attribute__((address_space(1))) unsigned int*)g,
      (__attribute__((address_space(3))) unsigned int*)l, 16, 0, 0);
}

__device__ inline unsigned short f2bf(float f) {
  union { float f; unsigned u; } c; c.f = f;
  unsigned r = c.u + 0x7FFFu + ((c.u >> 16) & 1u);  // RNE
  return (unsigned short)(r >> 16);
}

__device__ inline float bf2f(unsigned short u) {
  union { unsigned u; float f; } c; c.u = ((unsigned)u) << 16;
  return c.f;
}

// barrier that is ALSO a compiler-level memory fence
__device__ inline void block_barrier_fenced() {
  __builtin_amdgcn_s_barrier();
  asm volatile("" ::: "memory");
  __builtin_amdgcn_sched_barrier(0);
}

// ---- fused preprocessing: one launch, disjoint block ranges ---------------
#define PREP_LN_BLOCKS 8192
#define PREP_CV_BLOCKS 24576
#define PREP_TR_BLOCKS 24576
__global__ __launch_bounds__(256) void k_prep(const float* __restrict__ x,
                                              const float* __restrict__ pre_bias,
                                              const float* __restrict__ enc,
                                              const float* __restrict__ dec,
                                              unsigned short* __restrict__ xh,
                                              float* __restrict__ meanA,
                                              float* __restrict__ stdA,
                                              unsigned short* __restrict__ ench,
                                              unsigned short* __restrict__ dect) {
  int bid = blockIdx.x;
  int tid = threadIdx.x;

  if (bid < PREP_LN_BLOCKS) {
    int row = bid;
    int lane = tid & 63, wv = tid >> 6;
    const float* xr = x + (size_t)row * DIM;
    float a0 = xr[tid], a1 = xr[tid + 256], a2 = xr[tid + 512];
    __shared__ float red[8];
    float s = a0 + a1 + a2;
    for (int off = 32; off > 0; off >>= 1) s += __shfl_down(s, off);
    if (lane == 0) red[wv] = s;
    __syncthreads();
    float mean;
    if (tid == 0) { mean = (red[0] + red[1] + red[2] + red[3]) / (float)DIM; red[4] = mean; }
    __syncthreads();
    mean = red[4];
    float d0 = a0 - mean, d1 = a1 - mean, d2 = a2 - mean;
    float ss = d0 * d0 + d1 * d1 + d2 * d2;
    for (int off = 32; off > 0; off >>= 1) ss += __shfl_down(ss, off);
    if (lane == 0) red[wv] = ss;
    __syncthreads();
    float stdv;
    if (tid == 0) {
      float var = (red[0] + red[1] + red[2] + red[3]) / (float)DIM;
      stdv = sqrtf(var + 1e-5f);
      red[5] = stdv;
      meanA[row] = mean;
      stdA[row] = stdv;
    }
    __syncthreads();
    stdv = red[5];
    float inv = 1.0f / stdv;
    unsigned short* xo = xh + (size_t)row * DIM;
    xo[tid]       = f2bf(d0 * inv - pre_bias[tid]);
    xo[tid + 256] = f2bf(d1 * inv - pre_bias[tid + 256]);
    xo[tid + 512] = f2bf(d2 * inv - pre_bias[tid + 512]);
  } else if (bid < PREP_LN_BLOCKS + PREP_CV_BLOCKS) {
    int i = (bid - PREP_LN_BLOCKS) * 256 + tid;
    const int n4 = NF * DIM / 4;
    if (i < n4) {
      float4 v = ((const float4*)enc)[i];
      ushort4 r;
      r.x = f2bf(v.x); r.y = f2bf(v.y); r.z = f2bf(v.z); r.w = f2bf(v.w);
      ((ushort4*)ench)[i] = r;
    }
  } else {
    int local = bid - PREP_LN_BLOCKS - PREP_CV_BLOCKS;
    __shared__ float t[32][33];
    int tx = tid & 31, ty = tid >> 5;  // 32 x 8
    int fb = (local & 1023) * 32, cb = (local >> 10) * 32;
    for (int i = 0; i < 4; i++) {
      int r = ty + i * 8;
      t[r][tx] = dec[(size_t)(cb + r) * NF + fb + tx];
    }
    __syncthreads();
    for (int i = 0; i < 4; i++) {
      int r = ty + i * 8;
      dect[(size_t)(fb + r) * DIM + cb + tx] = f2bf(t[tx][r]);
    }
  }
}

// ---- 256x128 bf16 MFMA GEMM, BK=32, 3-buffer ring, 2-deep prefetch, -------
// ---- ONE barrier per K-step, counted vmcnt(3), 8 waves of 64x64, ----------
// ---- K-loop FULLY UNROLLED (round-18 proven: 514 us — FROZEN) -------------
// cand6[row][slice(256)][0..5] = (orderable_fp32_key & 0xFFFFFF00) | col7
// LDS: ring sA[3]x16K @0 + sB[3]x8K @49152 (72 KB); epilogue reuse:
//   sC[128][129] f32 @0 (66048 B) + m6[512][6] int @66048 (12288 B) = 78336
__global__ __launch_bounds__(512, 4) void k_gemm(const unsigned short* __restrict__ xh,
                                                 const unsigned short* __restrict__ ench,
                                                 const float* __restrict__ latent_bias,
                                                 unsigned* __restrict__ cand6) {
  __shared__ __align__(16) char smem[78336];
  int tid = threadIdx.x;
  int lane = tid & 63;
  int w = tid >> 6;
  int wr = w >> 1, wc = w & 1;      // 4 M-waves x 2 N-waves; wave out = 64x64
  int lid = blockIdx.x + blockIdx.y * gridDim.x;   // [0, 8192)
  int xcd = lid & 7;
  int u = (lid >> 3) & 31;          // position within 4(by) x 8(bx) super-tile
  int s = lid >> 8;                 // [0,32) super-tile sweep
  int bx = s * 8 + (u & 7);         // N tile (feature / 128) = slice index
  int by = xcd * 4 + (u >> 3);      // M tile (row / 256)
  const int fr = lane & 15, hi = lane >> 4;

  const char* Ab = (const char*)(xh + (size_t)by * 256 * DIM);
  const char* Bb = (const char*)(ench + (size_t)bx * 128 * DIM);

  int rA[2], cA[2], rB, cB;
#pragma unroll
  for (int i = 0; i < 2; i++) {
    int L = i * 8192 + tid * 16;
    int R = L >> 7;
    int ss = ((L >> 4) & 7) ^ (R & 7);
    rA[i] = (R << 1) + (ss >> 2);
    cA[i] = (ss & 3) << 4;
  }
  {
    int L = tid * 16;
    int R = L >> 7;
    int ss = ((L >> 4) & 7) ^ (R & 7);
    rB = (R << 1) + (ss >> 2);
    cB = (ss & 3) << 4;
  }

  int offA[4], offB[4];
#pragma unroll
  for (int m = 0; m < 4; m++) {
    int r = wr * 64 + m * 16 + fr;
    int R = r >> 1;
    int slot = ((r & 1) << 2) + hi;
    offA[m] = R * 128 + ((slot ^ (R & 7)) << 4);
  }
#pragma unroll
  for (int n = 0; n < 4; n++) {
    int r = wc * 64 + n * 16 + fr;
    int R = r >> 1;
    int slot = ((r & 1) << 2) + hi;
    offB[n] = R * 128 + ((slot ^ (R & 7)) << 4);
  }

  f32x4 acc[4][4];
#pragma unroll
  for (int m = 0; m < 4; m++)
#pragma unroll
    for (int n = 0; n < 4; n++) {
      f32x4 z = {0.f, 0.f, 0.f, 0.f};
      acc[m][n] = z;
    }

#define STAGE(kt, b)                                                          \
  do {                                                                        \
    char* dA = smem + (b) * 16384;                                            \
    char* dB = smem + 49152 + (b) * 8192;                                     \
    _Pragma("unroll") for (int i = 0; i < 2; i++)                             \
        async_ld16(Ab + (size_t)rA[i] * (DIM * 2) + (kt) * 64 + cA[i],        \
                   dA + i * 8192 + tid * 16);                                 \
    async_ld16(Bb + (size_t)rB * (DIM * 2) + (kt) * 64 + cB,                  \
               dB + tid * 16);                                                \
  } while (0)

  // prologue: 2 tiles in flight (2-deep prefetch)
  STAGE(0, 0);
  STAGE(1, 1);

#pragma unroll
  for (int kt = 0; kt < 24; kt++) {
    int b = kt % 3;
    if (kt + 1 < 24) asm volatile("s_waitcnt vmcnt(3)" ::: "memory");
    else             asm volatile("s_waitcnt vmcnt(0)" ::: "memory");
    block_barrier_fenced();
    if (kt + 2 < 24) STAGE(kt + 2, (kt + 2) % 3);

    const char* pA = smem + b * 16384;
    const char* pB = smem + 49152 + b * 8192;
    bf16x8 af[4], bv[4];
#pragma unroll
    for (int m = 0; m < 4; m++) af[m] = *(const bf16x8*)(pA + offA[m]);
#pragma unroll
    for (int n = 0; n < 4; n++) bv[n] = *(const bf16x8*)(pB + offB[n]);
    __builtin_amdgcn_s_setprio(1);
#pragma unroll
    for (int m = 0; m < 4; m++)
#pragma unroll
      for (int n = 0; n < 4; n++)
        acc[m][n] = __builtin_amdgcn_mfma_f32_16x16x32_bf16(af[m], bv[n], acc[m][n], 0, 0, 0);
    __builtin_amdgcn_s_setprio(0);
  }
#undef STAGE
  __syncthreads();  // all compute(23) reads done before ring is reused as sC

  // ---- fused epilogue: two 128-row half-passes over the 256x128 output ----
  float* sC = (float*)smem;                 // [128][129]
  int* m6 = (int*)(smem + 66048);           // [512][6], slot = q*128 + r
#pragma unroll
  for (int p = 0; p < 2; p++) {
    if ((wr >> 1) == p) {
#pragma unroll
      for (int n = 0; n < 4; n++) {
        int lcol = wc * 64 + n * 16 + fr;
        float lbv = latent_bias[bx * 128 + lcol];
#pragma unroll
        for (int m = 0; m < 4; m++) {
          int lr = (wr & 1) * 64 + m * 16 + hi * 4;
#pragma unroll
          for (int j = 0; j < 4; j++)
            sC[(lr + j) * 129 + lcol] = acc[m][n][j] + lbv;
        }
      }
    }
    __syncthreads();
    {
      int r = tid & 127, q = tid >> 7;
      const float* cr = sC + r * 129 + q * 32;
      unsigned c0 = 0, c1 = 0, c2 = 0, c3 = 0, c4 = 0, c5 = 0;
      for (int c = 0; c < 32; c++) {
        union { float f; unsigned u; } cv; cv.f = cr[c];
        unsigned key = ((int)cv.u < 0) ? ~cv.u : (cv.u | 0x80000000u);
        unsigned pk = (key & 0xFFFFFF00u) | (unsigned)(q * 32 + c);
        if (pk > c0) {
          bool b1 = pk > c1, b2 = pk > c2, b3 = pk > c3, b4 = pk > c4, b5 = pk > c5;
          c0 = b1 ? c1 : pk;
          c1 = b1 ? (b2 ? c2 : pk) : c1;
          c2 = b2 ? (b3 ? c3 : pk) : c2;
          c3 = b3 ? (b4 ? c4 : pk) : c3;
          c4 = b4 ? (b5 ? c5 : pk) : c4;
          c5 = b5 ? pk : c5;
        }
      }
      int* mp = m6 + (q * 128 + r) * 6;
      mp[0] = (int)c0; mp[1] = (int)c1; mp[2] = (int)c2;
      mp[3] = (int)c3; mp[4] = (int)c4; mp[5] = (int)c5;
    }
    __syncthreads();
    if (tid < 128) {
      const int* L0 = m6 + (0 * 128 + tid) * 6;
      const int* L1 = m6 + (1 * 128 + tid) * 6;
      const int* L2 = m6 + (2 * 128 + tid) * 6;
      const int* L3 = m6 + (3 * 128 + tid) * 6;
      int i0 = 5, i1 = 5, i2 = 5, i3 = 5;
      unsigned* dst = cand6 + ((size_t)(by * 256 + p * 128 + tid) * 256 + bx) * 6;
#pragma unroll
      for (int k = 0; k < 6; k++) {
        unsigned v0 = (i0 >= 0) ? (unsigned)L0[i0] : 0u;
        unsigned v1 = (i1 >= 0) ? (unsigned)L1[i1] : 0u;
        unsigned v2 = (i2 >= 0) ? (unsigned)L2[i2] : 0u;
        unsigned v3 = (i3 >= 0) ? (unsigned)L3[i3] : 0u;
        unsigned best = v0; int bq = 0;
        if (v1 > best) { best = v1; bq = 1; }
        if (v2 > best) { best = v2; bq = 2; }
        if (v3 > best) { best = v3; bq = 3; }
        dst[k] = best;
        if (bq == 0) i0--; else if (bq == 1) i1--; else if (bq == 2) i2--; else i3--;
      }
    }
    __syncthreads();
  }
}

// --- fused screen + refine + top-32 + decode (round-17 proven — FROZEN) ----
__global__ __launch_bounds__(256) void k_sel(const float* __restrict__ x,
                                             const float* __restrict__ pre_bias,
                                             const float* __restrict__ latent_bias,
                                             const float* __restrict__ enc,
                                             const unsigned short* __restrict__ dect,
                                             const unsigned* __restrict__ cand6,
                                             const float* __restrict__ meanA,
                                             const float* __restrict__ stdA,
                                             float* __restrict__ out) {
  __shared__ __align__(16) float xn[DIM];
  __shared__ int hist[512];
  __shared__ int hist2[128];
  __shared__ int sb_bstar, sb_chi, sb_cnt;
  __shared__ unsigned sb_tau;
  __shared__ int cand[CANDCAP];
  __shared__ float exactv[128];
  __shared__ int self_[128];
  __shared__ float hv[TOPK];
  __shared__ int hf[TOPK];

  int row = blockIdx.x, tid = threadIdx.x, lane = tid & 63;
  float m = meanA[row], s = stdA[row], inv = 1.0f / s;
  const float* xr = x + (size_t)row * DIM;
  for (int i = tid; i < DIM; i += 256)
    xn[i] = (xr[i] - m) * inv - pre_bias[i];

  // ---------------- screen phase (LDS-resident) ---------------------------
  const unsigned* src = cand6 + (size_t)row * 1536 + tid * 6;
  unsigned pc0 = src[0], pc1 = src[1], pc2 = src[2],
           pc3 = src[3], pc4 = src[4], pc5 = src[5];

  hist[tid] = 0; hist[tid + 256] = 0;
  if (tid < 128) hist2[tid] = 0;
  if (tid == 0) sb_cnt = 0;
  __syncthreads();

  atomicAdd(&hist[pc0 >> 23], 1);
  atomicAdd(&hist[pc1 >> 23], 1);
  atomicAdd(&hist[pc2 >> 23], 1);
  atomicAdd(&hist[pc3 >> 23], 1);
  atomicAdd(&hist[pc4 >> 23], 1);
  atomicAdd(&hist[pc5 >> 23], 1);
  __syncthreads();

  if (tid < 64) {
    int b = lane * 8;
    int h0 = hist[b], h1 = hist[b+1], h2 = hist[b+2], h3 = hist[b+3];
    int h4 = hist[b+4], h5 = hist[b+5], h6 = hist[b+6], h7 = hist[b+7];
    int s7 = h7, s6 = h6 + s7, s5 = h5 + s6, s4 = h4 + s5;
    int s3 = h3 + s4, s2 = h2 + s3, s1 = h1 + s2, s0 = h0 + s1;
    int tot = s0, acc = tot;
#pragma unroll
    for (int off = 1; off <= 32; off <<= 1) {
      int t = __shfl_down(acc, off);
      if (lane + off < 64) acc += t;
    }
    int excl = acc - tot;
    int best = -1, bs = 0, hb = 0;
    if (excl + s0 >= RTHRESH) { best = b + 0; bs = excl + s0; hb = h0; }
    if (excl + s1 >= RTHRESH) { best = b + 1; bs = excl + s1; hb = h1; }
    if (excl + s2 >= RTHRESH) { best = b + 2; bs = excl + s2; hb = h2; }
    if (excl + s3 >= RTHRESH) { best = b + 3; bs = excl + s3; hb = h3; }
    if (excl + s4 >= RTHRESH) { best = b + 4; bs = excl + s4; hb = h4; }
    if (excl + s5 >= RTHRESH) { best = b + 5; bs = excl + s5; hb = h5; }
    if (excl + s6 >= RTHRESH) { best = b + 6; bs = excl + s6; hb = h6; }
    if (excl + s7 >= RTHRESH) { best = b + 7; bs = excl + s7; hb = h7; }
#pragma unroll
    for (int off = 32; off > 0; off >>= 1) {
      int ob = __shfl_down(best, off), obs = __shfl_down(bs, off), ohb = __shfl_down(hb, off);
      if (lane + off < 64 && ob > best) { best = ob; bs = obs; hb = ohb; }
    }
    if (lane == 0) { sb_bstar = best; sb_chi = bs - hb; }
  }
  __syncthreads();
  int bstar = sb_bstar, chi = sb_chi;

  if ((int)(pc0 >> 23) == bstar) atomicAdd(&hist2[(pc0 >> 16) & 127], 1);
  if ((int)(pc1 >> 23) == bstar) atomicAdd(&hist2[(pc1 >> 16) & 127], 1);
  if ((int)(pc2 >> 23) == bstar) atomicAdd(&hist2[(pc2 >> 16) & 127], 1);
  if ((int)(pc3 >> 23) == bstar) atomicAdd(&hist2[(pc3 >> 16) & 127], 1);
  if ((int)(pc4 >> 23) == bstar) atomicAdd(&hist2[(pc4 >> 16) & 127], 1);
  if ((int)(pc5 >> 23) == bstar) atomicAdd(&hist2[(pc5 >> 16) & 127], 1);
  __syncthreads();

  if (tid < 64) {
    int g0 = hist2[lane * 2], g1 = hist2[lane * 2 + 1];
    int s1 = g1, s0 = g0 + g1;
    int tot = s0, acc = tot;
#pragma unroll
    for (int off = 1; off <= 32; off <<= 1) {
      int t = __shfl_down(acc, off);
      if (lane + off < 64) acc += t;
    }
    int excl = acc - tot;
    int best = -1;
    if (chi + excl + s0 >= RTHRESH) best = lane * 2;
    if (chi + excl + s1 >= RTHRESH) best = lane * 2 + 1;
#pragma unroll
    for (int off = 32; off > 0; off >>= 1) {
      int ob = __shfl_down(best, off);
      if (lane + off < 64 && ob > best) best = ob;
    }
    if (lane == 0) sb_tau = ((unsigned)((bstar << 7) | best)) << 16;
  }
  __syncthreads();

  unsigned tau = sb_tau;
#define EMIT(PC)                                                   \
  if ((PC) >= tau) {                                               \
    int pos = atomicAdd(&sb_cnt, 1);                               \
    if (pos < CANDCAP) cand[pos] = tid * 128 + (int)((PC) & 127u); \
  }
  EMIT(pc0) EMIT(pc1) EMIT(pc2) EMIT(pc3) EMIT(pc4) EMIT(pc5)
#undef EMIT
  __syncthreads();

  int cnt = sb_cnt < CANDCAP ? sb_cnt : CANDCAP;  // in [RTHRESH, CANDCAP]
  if (tid < 128) {
    self_[tid] = (tid < cnt) ? cand[tid] : 0x7FFFFFF;
    exactv[tid] = -3.0e38f;
  }
  __syncthreads();

  // ---------------- refine phase (FROZEN order; unroll 8 = bit-exact) -----
#pragma unroll
  for (int pass = 0; pass < 2; pass++) {
    int g = pass * 64 + (tid >> 2), t4 = tid & 3;
    if (g < cnt) {
      int f = self_[g];
      const float4* xp = (const float4*)xn;
      const float4* wp = (const float4*)(enc + (size_t)f * DIM);
      float acc = 0.f;
#pragma unroll 8
      for (int i = t4; i < DIM / 4; i += 4) {
        float4 a = xp[i], b = wp[i];
        acc = fmaf(a.x, b.x, acc);
        acc = fmaf(a.y, b.y, acc);
        acc = fmaf(a.z, b.z, acc);
        acc = fmaf(a.w, b.w, acc);
      }
      acc += __shfl_xor(acc, 1);
      acc += __shfl_xor(acc, 2);
      if (t4 == 0) exactv[g] = acc + latent_bias[f];
    }
  }
  __syncthreads();

  // ---------------- exact top-32 (FROZEN) ---------------------------------
  if (tid < 64) {
    float v0 = exactv[lane];      int f0 = self_[lane];
    float v1 = exactv[lane + 64]; int f1 = self_[lane + 64];
    for (int r = 0; r < TOPK; r++) {
      float bv = v0; int bf = f0;
      if (v1 > bv || (v1 == bv && f1 < bf)) { bv = v1; bf = f1; }
#pragma unroll
      for (int off = 32; off > 0; off >>= 1) {
        float ov = __shfl_down(bv, off);
        int of = __shfl_down(bf, off);
        if (lane + off < 64 && (ov > bv || (ov == bv && of < bf))) { bv = ov; bf = of; }
      }
      bv = __shfl(bv, 0);
      bf = __shfl(bf, 0);
      if (lane == 0) { hv[r] = bv > 0.f ? bv : 0.f; hf[r] = bf; }
      if (f0 == bf) v0 = -3.0e38f;
      if (f1 == bf) v1 = -3.0e38f;
    }
  }
  __syncthreads();

  // ---------------- decode + de-normalize (FROZEN) ------------------------
  float* orow = out + (size_t)row * DIM;
#pragma unroll
  for (int t = 0; t < 3; t++) {
    int c = tid + t * 256;
    float acc = pre_bias[c];
    for (int j = 0; j < TOPK; j++)
      acc = fmaf(hv[j], bf2f(dect[(size_t)hf[j] * DIM + c]), acc);
    orow[c] = acc * s + m;
  }
}

extern "C" void kernel_launch(void* const* d_in, const int* in_sizes, int n_in,
                              void* d_out, int out_size, void* d_ws, size_t ws_size,
                              hipStream_t stream) {
  const float* x   = (const float*)d_in[0];
  const float* pb  = (const float*)d_in[1];
  const float* lb  = (const float*)d_in[2];
  const float* enc = (const float*)d_in[3];
  const float* dec = (const float*)d_in[4];
  float* out = (float*)d_out;

  // fixed workspace layout (bytes)
  const size_t off_xh   = 0;            // 12,582,912
  const size_t off_ench = 12582912;     // 50,331,648
  const size_t off_dect = 62914560;     // 50,331,648 (bf16)
  const size_t off_mean = 113246208;    // 32,768
  const size_t off_std  = 113278976;    // 32,768
  const size_t off_c6   = 113311744;    // 8192*256*6*4 = 50,331,648
  if (ws_size < 163643392) return;      // cannot run

  char* ws = (char*)d_ws;
  unsigned short* xh   = (unsigned short*)(ws + off_xh);
  unsigned short* ench = (unsigned short*)(ws + off_ench);
  unsigned short* dect = (unsigned short*)(ws + off_dect);
  float* meanA = (float*)(ws + off_mean);
  float* stdA  = (float*)(ws + off_std);
  unsigned* cand6 = (unsigned*)(ws + off_c6);

  hipLaunchKernelGGL(k_prep,
                     dim3(PREP_LN_BLOCKS + PREP_CV_BLOCKS + PREP_TR_BLOCKS),
                     dim3(256), 0, stream,
                     x, pb, enc, dec, xh, meanA, stdA, ench, dect);

  hipLaunchKernelGGL(k_gemm, dim3(NF / 128, N_ROWS / 256), dim3(512), 0, stream,
                     xh, ench, lb, cand6);

  hipLaunchKernelGGL(k_sel, dim3(N_ROWS), dim3(256), 0, stream,
                     x, pb, lb, enc, dect, cand6, meanA, stdA, out);
}